// Round 7
// baseline (352.423 us; speedup 1.0000x reference)
//
#include <hip/hip_runtime.h>

// VectorQuantizer forward: inputs [64,2048,64] f32, codebook [1024,64] f32.
// Outputs (f32, concat): quantized_ste [8388608], loss [1], indices-as-float [131072].
//
// Round 15: R14 (MFMA, 163us) is latency-bound, not pipe-bound: VALUBusy 30%
// + MfmaUtil 13%, HBM 5%, conflicts 0 -- and grid 1024 = 4 blocks/CU = 16
// waves/CU = 50% occupancy CAP (measured 43%). The 6-MFMA acc chain is
// latency-serialized and 4 waves/SIMD can't hide it. Fix: halve rows/wave
// (16 = one MFMA rowtile), 64 rows/block, grid 2048 = 8 blocks/CU = 32
// waves/CU (100% cap). Per-wave state halves -> VGPR ~55 under the 64 cap
// of __launch_bounds__(256,8). B traffic doubles (2.1GB via L1/L2) but
// co-sweeping waves hit L1; latency hiding doubles.
//
// Numerics: identical to R14. bf16 hi/lo split, 3-term mfma_f32_16x16x32_bf16
// (|dot err| <= ~2e-6); argmin filter on m=cs-2dot quantized to u32 key
// ((m*2^18+bias)<<10|idx), top-3 per row via min/max network; rows with
// gap12 within the asq-scaled margin recompute EXACT d2 (sequential fmaf
// k=0..63, fl(fl(asq-2acc)+cs), u64 first-index-wins) for <=3 candidates.
// C/D layout: col=lane&15, row=(lane>>4)*4+reg (HW-verified). Loss/STE
// epilogue in identical 64-row units (2048 identical partials).

#define NROWS  131072
#define DIM    64
#define KCB    1024
#define QSIZE  (NROWS * DIM)  // 8388608

typedef unsigned long long u64;
typedef unsigned int u32;
typedef unsigned short ushortx;
typedef __attribute__((ext_vector_type(8))) short short8v;
typedef __attribute__((ext_vector_type(4))) float f32x4;

__device__ __forceinline__ u32 umin32(u32 a, u32 b) { return a < b ? a : b; }
__device__ __forceinline__ u32 umax32(u32 a, u32 b) { return a > b ? a : b; }

// RNE f32 -> bf16 (deterministic, internal-only precision split)
__device__ __forceinline__ ushortx f2bf(float f) {
    u32 u = __float_as_uint(f);
    u32 r = u + 0x7FFFu + ((u >> 16) & 1u);
    return (ushortx)(r >> 16);
}
__device__ __forceinline__ float bf2f(ushortx h) {
    return __uint_as_float(((u32)h) << 16);
}

// ---- prep: csq (exact quarter chains), cs18b key bias, bf16 hi/lo split ----
__global__ __launch_bounds__(256) void vq_prep(const float* __restrict__ cb,
                                               float* __restrict__ csq,
                                               float* __restrict__ cs18b,
                                               ushortx* __restrict__ cbh,
                                               ushortx* __restrict__ cbl,
                                               float* __restrict__ loss_slot) {
    int k = blockIdx.x * 256 + threadIdx.x;
    if (k < KCB) {
        const float* c = cb + k * DIM;
        float a0 = 0.f, a1 = 0.f, a2 = 0.f, a3 = 0.f;
        #pragma unroll
        for (int d = 0; d < 16; ++d) {
            a0 = fmaf(c[d],      c[d],      a0);
            a1 = fmaf(c[16 + d], c[16 + d], a1);
            a2 = fmaf(c[32 + d], c[32 + d], a2);
            a3 = fmaf(c[48 + d], c[48 + d], a3);
        }
        const float cs = (a0 + a1) + (a2 + a3);
        csq[k] = cs;
        cs18b[k] = cs * 262144.0f + 131072.0f;   // m*2^18 + bias stays in [0,2^18)
        #pragma unroll 4
        for (int d = 0; d < DIM; ++d) {
            const float f = c[d];
            const ushortx h = f2bf(f);
            cbh[k * DIM + d] = h;
            cbl[k * DIM + d] = f2bf(f - bf2f(h));
        }
    }
    if (blockIdx.x == 0 && threadIdx.x == 0) *loss_slot = 0.f;
}

// ---- main: 256 threads = 4 waves; block = 64 rows (wave owns 16 rows,
// ---- sweeps all 1024 codes; grid 2048 = 8 blocks/CU = 32 waves/CU) ----
__global__ __launch_bounds__(256, 8) void vq_main(const float* __restrict__ x,
                                                  const float* __restrict__ cb,
                                                  const float* __restrict__ csq,
                                                  const float* __restrict__ cs18b,
                                                  const ushortx* __restrict__ cbh,
                                                  const ushortx* __restrict__ cbl,
                                                  float* __restrict__ out_q,
                                                  float* __restrict__ out_loss,
                                                  float* __restrict__ out_idx) {
    __shared__ u32   sTop[4][16][3];
    __shared__ int   sFinal[64];
    __shared__ float sLoss[4];

    const int tid  = threadIdx.x;
    const int lane = tid & 63;
    const int wid  = tid >> 6;            // 0..3
    const size_t rowbase = (size_t)blockIdx.x * 64;
    const int wrow0 = wid * 16;           // block-local first row of this wave
    const int lcol  = lane & 15;          // A-row-in-tile / B-col / D-col
    const int lkq   = lane >> 4;          // k-chunk 0..3

    // ---- A fragments: 2 k-halves, hi/lo bf16 splits ----
    short8v Ah[2], Al[2];
    #pragma unroll
    for (int h = 0; h < 2; ++h) {
        const float* xp = x + (rowbase + (size_t)(wrow0 + lcol)) * DIM
                          + h * 32 + lkq * 8;
        const float4 u0 = *reinterpret_cast<const float4*>(xp);
        const float4 u1 = *reinterpret_cast<const float4*>(xp + 4);
        const float xv[8] = {u0.x, u0.y, u0.z, u0.w, u1.x, u1.y, u1.z, u1.w};
        union { ushortx u[8]; short8v v; } uh, ul;
        #pragma unroll
        for (int j = 0; j < 8; ++j) {
            const ushortx hh = f2bf(xv[j]);
            uh.u[j] = hh;
            ul.u[j] = f2bf(xv[j] - bf2f(hh));
        }
        Ah[h] = uh.v;
        Al[h] = ul.v;
    }

    // ---- code sweep: top-3 u32 keys per row-slot (4 slots/lane) ----
    u32 k1[4], k2[4], k3[4];
    #pragma unroll
    for (int s = 0; s < 4; ++s) { k1[s] = ~0u; k2[s] = ~0u; k3[s] = ~0u; }

    u32 nlane = (u32)lcol;
    const ushortx* bhp = cbh + (size_t)lcol * DIM + lkq * 8;
    const ushortx* blp = cbl + (size_t)lcol * DIM + lkq * 8;

    #pragma unroll 1
    for (int ct = 0; ct < 64; ++ct) {     // 16 codes per tile
        const short8v Bh0 = *reinterpret_cast<const short8v*>(bhp);
        const short8v Bh1 = *reinterpret_cast<const short8v*>(bhp + 32);
        const short8v Bl0 = *reinterpret_cast<const short8v*>(blp);
        const short8v Bl1 = *reinterpret_cast<const short8v*>(blp + 32);
        const float csb = cs18b[nlane];
        f32x4 acc = (f32x4){0.f, 0.f, 0.f, 0.f};
        acc = __builtin_amdgcn_mfma_f32_16x16x32_bf16(Ah[0], Bh0, acc, 0, 0, 0);
        acc = __builtin_amdgcn_mfma_f32_16x16x32_bf16(Al[0], Bh0, acc, 0, 0, 0);
        acc = __builtin_amdgcn_mfma_f32_16x16x32_bf16(Ah[0], Bl0, acc, 0, 0, 0);
        acc = __builtin_amdgcn_mfma_f32_16x16x32_bf16(Ah[1], Bh1, acc, 0, 0, 0);
        acc = __builtin_amdgcn_mfma_f32_16x16x32_bf16(Al[1], Bh1, acc, 0, 0, 0);
        acc = __builtin_amdgcn_mfma_f32_16x16x32_bf16(Ah[1], Bl1, acc, 0, 0, 0);
        #pragma unroll
        for (int r = 0; r < 4; ++r) {
            const float m18 = fmaf(acc[r], -524288.0f, csb);  // (cs-2dot)*2^18+bias
            const u32 key = ((u32)m18 << 10) | nlane;          // trunc-cvt, monotone
            const u32 nk1 = umin32(key, k1[r]);
            const u32 mx  = umax32(key, k1[r]);
            const u32 nk2 = umin32(k2[r], mx);
            const u32 mx2 = umax32(k2[r], mx);
            k3[r] = umin32(k3[r], mx2);
            k1[r] = nk1; k2[r] = nk2;
        }
        bhp += 16 * DIM; blp += 16 * DIM; nlane += 16;
    }

    // ---- merge the 16 col-classes per row (butterfly over lanes 16g..16g+15) ----
    #pragma unroll
    for (int s = 0; s < 4; ++s) {
        u32 a1 = k1[s], a2 = k2[s], a3 = k3[s];
        #pragma unroll
        for (int mask = 1; mask <= 8; mask <<= 1) {
            const u32 b1 = __shfl_xor(a1, mask, 64);
            const u32 b2 = __shfl_xor(a2, mask, 64);
            const u32 b3 = __shfl_xor(a3, mask, 64);
            const u32 c1 = umin32(a1, b1), d1 = umax32(a1, b1);
            const u32 c2 = umin32(a2, b2);
            const u32 o3 = umin32(umax32(d1, c2), umin32(a3, b3));
            a1 = c1; a2 = umin32(d1, c2); a3 = o3;
        }
        k1[s] = a1; k2[s] = a2; k3[s] = a3;
    }
    if (lcol < 4) {   // lane 16g+j writes slot j -> row g*4 + j
        const int j = lcol, g = lkq;
        const int row = g * 4 + j;
        sTop[wid][row][0] = k1[j]; sTop[wid][row][1] = k2[j]; sTop[wid][row][2] = k3[j];
    }
    __syncthreads();

    // ---- per-row final: non-hot -> min1; hot -> exact d2 (R12 chain) on candidates ----
    if (lane < 16) {
        const int row = wrow0 + lane;                  // block-local 0..63
        const u32 K1 = sTop[wid][lane][0];
        const u32 K2 = sTop[wid][lane][1];
        const u32 K3 = sTop[wid][lane][2];
        int idx = (int)(K1 & 1023u);
        const u32 m1q = K1 >> 10, m2q = K2 >> 10;
        if (m2q - m1q <= 26u) {                        // coarse hot (covers asq<=166)
            const float* xr = x + (rowbase + (size_t)row) * DIM;
            float4 xv[16];
            #pragma unroll
            for (int q = 0; q < 16; ++q) xv[q] = reinterpret_cast<const float4*>(xr)[q];
            float p[4];
            #pragma unroll
            for (int q = 0; q < 4; ++q) {              // exact quarter chains
                float a = 0.f;
                #pragma unroll
                for (int e = 0; e < 4; ++e) {
                    const float4 v = xv[4 * q + e];
                    a = fmaf(v.x, v.x, a); a = fmaf(v.y, v.y, a);
                    a = fmaf(v.z, v.z, a); a = fmaf(v.w, v.w, a);
                }
                p[q] = a;
            }
            const float asq = (p[0] + p[1]) + (p[2] + p[3]);
            const u32 Mq = (u32)fmaf(asq, 0.126f, 5.0f);   // safe ulp-derived margin
            u64 best = ~0ull;
            #pragma unroll 1
            for (int c = 0; c < 3; ++c) {
                const u32 Kc = c == 0 ? K1 : (c == 1 ? K2 : K3);
                const u32 mq = Kc >> 10;
                if (c > 0 && (mq - m1q) > Mq) break;   // keys sorted: later ones farther
                const int n = (int)(Kc & 1023u);
                const float4* cr = reinterpret_cast<const float4*>(cb + (size_t)n * DIM);
                float acc = 0.f;
                #pragma unroll
                for (int q = 0; q < 16; ++q) {         // exact sequential k-chain 0..63
                    const float4 c4 = cr[q], v = xv[q];
                    acc = fmaf(v.x, c4.x, acc); acc = fmaf(v.y, c4.y, acc);
                    acc = fmaf(v.z, c4.z, acc); acc = fmaf(v.w, c4.w, acc);
                }
                const float tt = asq - 2.0f * acc;     // ref rounding 1
                const float dd = tt + csq[n];          // ref rounding 2
                const u64 kk = ((u64)__float_as_uint(dd) << 32) | (u32)n;
                best = kk < best ? kk : best;
            }
            idx = (int)(u32)best;
        }
        sFinal[row] = idx;
        out_idx[rowbase + row] = (float)idx;
    }
    __syncthreads();

    // ---- epilogue: STE + loss in the identical 64-row unit (1 per block) ----
    {
        const size_t base = rowbase * DIM;
        float lsum = 0.f;
        #pragma unroll 4
        for (int i = tid; i < 64 * DIM; i += 256) {
            const int r = i >> 6;
            const int d = i & 63;
            const int kb = sFinal[r];
            const float q  = cb[(size_t)kb * DIM + d];
            const float xe = x[base + i];
            out_q[base + i] = xe + (q - xe);            // STE forward, ref's rounding
            const float df = q - xe;
            lsum = fmaf(df, df, lsum);
        }
        #pragma unroll
        for (int off = 32; off; off >>= 1) lsum += __shfl_down(lsum, off, 64);
        if (lane == 0) sLoss[wid] = lsum;
        __syncthreads();
        if (tid == 0) {
            const float tot = (sLoss[0] + sLoss[1]) + (sLoss[2] + sLoss[3]);
            atomicAdd(out_loss, tot * (1.25f / 8388608.0f));
        }
    }
}

extern "C" void kernel_launch(void* const* d_in, const int* in_sizes, int n_in,
                              void* d_out, int out_size, void* d_ws, size_t ws_size,
                              hipStream_t stream) {
    const float* x  = (const float*)d_in[0];   // 8388608
    const float* cb = (const float*)d_in[1];   // 65536
    float* out      = (float*)d_out;
    float* out_loss = out + QSIZE;             // [8388608]
    float* out_idx  = out + QSIZE + 1;         // [8388609 .. 8519680]

    float*   csq   = (float*)d_ws;             // 1024 f32
    float*   cs18b = csq + 1024;               // 1024 f32
    ushortx* cbh   = (ushortx*)(csq + 2048);   // 1024*64 bf16-hi (128 KB)
    ushortx* cbl   = cbh + KCB * DIM;          // 1024*64 bf16-lo (128 KB)

    vq_prep<<<4, 256, 0, stream>>>(cb, csq, cs18b, cbh, cbl, out_loss);
    vq_main<<<NROWS / 64, 256, 0, stream>>>(x, cb, csq, cs18b, cbh, cbl,
                                            out, out_loss, out_idx);
}

// Round 8
// 234.410 us; speedup vs baseline: 1.5034x; 1.5034x over previous
//
#include <hip/hip_runtime.h>

// VectorQuantizer forward: inputs [64,2048,64] f32, codebook [1024,64] f32.
// Outputs (f32, concat): quantized_ste [8388608], loss [1], indices-as-float [131072].
//
// Round 16: R15 (8 blocks/CU, 1 rowtile/wave) REGRESSED 163->283us at 88%
// occupancy with identical absolute pipe-busy time (VALU ~50us, MFMA ~21us
// in both) -> occupancy was never the binder; R15 lost MFMA ILP (2 chains->1)
// and (256,8) crushed VGPR to 32 (spill traffic +12MB). Real R14 binder:
// lockstep waves with NO cross-iteration prefetch -> all waves expose the
// ~200-400cy L2 latency of the 4 B-loads every ct (convoy). Fix: R14 base +
// register double-buffer of B fragments and csb (issue ct+1 loads before
// ct's 12-MFMA compute; #pragma unroll 2 gives even/odd reg sets, no movs).
// +~18 VGPR under the (256,4) cap; occupancy unchanged.
//
// Numerics: identical to R14/R15. bf16 hi/lo split, 3-term
// mfma_f32_16x16x32_bf16 (|dot err| <= ~2e-6); argmin filter on m=cs-2dot
// quantized to u32 key ((m*2^18+bias)<<10|idx), top-3 per row via min/max
// network; rows with gap12 within the asq-scaled margin recompute EXACT d2
// (sequential fmaf k=0..63, fl(fl(asq-2acc)+cs), u64 first-index-wins) for
// <=3 candidates. C/D layout: col=lane&15, row=(lane>>4)*4+reg (HW-verified).
// Loss/STE epilogue in identical 64-row units (2048 identical partials).

#define NROWS  131072
#define DIM    64
#define KCB    1024
#define QSIZE  (NROWS * DIM)  // 8388608

typedef unsigned long long u64;
typedef unsigned int u32;
typedef unsigned short ushortx;
typedef __attribute__((ext_vector_type(8))) short short8v;
typedef __attribute__((ext_vector_type(4))) float f32x4;

__device__ __forceinline__ u32 umin32(u32 a, u32 b) { return a < b ? a : b; }
__device__ __forceinline__ u32 umax32(u32 a, u32 b) { return a > b ? a : b; }

// RNE f32 -> bf16 (deterministic, internal-only precision split)
__device__ __forceinline__ ushortx f2bf(float f) {
    u32 u = __float_as_uint(f);
    u32 r = u + 0x7FFFu + ((u >> 16) & 1u);
    return (ushortx)(r >> 16);
}
__device__ __forceinline__ float bf2f(ushortx h) {
    return __uint_as_float(((u32)h) << 16);
}

// ---- prep: csq (exact quarter chains), cs18b key bias, bf16 hi/lo split ----
__global__ __launch_bounds__(256) void vq_prep(const float* __restrict__ cb,
                                               float* __restrict__ csq,
                                               float* __restrict__ cs18b,
                                               ushortx* __restrict__ cbh,
                                               ushortx* __restrict__ cbl,
                                               float* __restrict__ loss_slot) {
    int k = blockIdx.x * 256 + threadIdx.x;
    if (k < KCB) {
        const float* c = cb + k * DIM;
        float a0 = 0.f, a1 = 0.f, a2 = 0.f, a3 = 0.f;
        #pragma unroll
        for (int d = 0; d < 16; ++d) {
            a0 = fmaf(c[d],      c[d],      a0);
            a1 = fmaf(c[16 + d], c[16 + d], a1);
            a2 = fmaf(c[32 + d], c[32 + d], a2);
            a3 = fmaf(c[48 + d], c[48 + d], a3);
        }
        const float cs = (a0 + a1) + (a2 + a3);
        csq[k] = cs;
        cs18b[k] = cs * 262144.0f + 131072.0f;   // m*2^18 + bias stays in [0,2^18)
        #pragma unroll 4
        for (int d = 0; d < DIM; ++d) {
            const float f = c[d];
            const ushortx h = f2bf(f);
            cbh[k * DIM + d] = h;
            cbl[k * DIM + d] = f2bf(f - bf2f(h));
        }
    }
    if (blockIdx.x == 0 && threadIdx.x == 0) *loss_slot = 0.f;
}

// ---- main: 256 threads = 4 waves; block = 128 rows (wave owns 32 rows =
// ---- 2 MFMA rowtiles -> 2 independent acc chains; sweeps all 1024 codes) ----
__global__ __launch_bounds__(256, 4) void vq_main(const float* __restrict__ x,
                                                  const float* __restrict__ cb,
                                                  const float* __restrict__ csq,
                                                  const float* __restrict__ cs18b,
                                                  const ushortx* __restrict__ cbh,
                                                  const ushortx* __restrict__ cbl,
                                                  float* __restrict__ out_q,
                                                  float* __restrict__ out_loss,
                                                  float* __restrict__ out_idx) {
    __shared__ u32   sTop[4][32][3];
    __shared__ int   sFinal[128];
    __shared__ float sLoss[4];

    const int tid  = threadIdx.x;
    const int lane = tid & 63;
    const int wid  = tid >> 6;            // 0..3
    const size_t rowbase = (size_t)blockIdx.x * 128;
    const int wrow0 = wid * 32;           // block-local first row of this wave
    const int lcol  = lane & 15;          // A-row-in-tile / B-col / D-col
    const int lkq   = lane >> 4;          // k-chunk 0..3

    // ---- A fragments: 2 rowtiles x 2 k-halves, hi/lo bf16 splits ----
    short8v Ah[2][2], Al[2][2];
    #pragma unroll
    for (int t = 0; t < 2; ++t)
        #pragma unroll
        for (int h = 0; h < 2; ++h) {
            const float* xp = x + (rowbase + (size_t)(wrow0 + t * 16 + lcol)) * DIM
                              + h * 32 + lkq * 8;
            const float4 u0 = *reinterpret_cast<const float4*>(xp);
            const float4 u1 = *reinterpret_cast<const float4*>(xp + 4);
            const float xv[8] = {u0.x, u0.y, u0.z, u0.w, u1.x, u1.y, u1.z, u1.w};
            union { ushortx u[8]; short8v v; } uh, ul;
            #pragma unroll
            for (int j = 0; j < 8; ++j) {
                const ushortx hh = f2bf(xv[j]);
                uh.u[j] = hh;
                ul.u[j] = f2bf(xv[j] - bf2f(hh));
            }
            Ah[t][h] = uh.v;
            Al[t][h] = ul.v;
        }

    // ---- code sweep: top-3 u32 keys per row-slot (8 slots/lane) ----
    u32 k1[8], k2[8], k3[8];
    #pragma unroll
    for (int s = 0; s < 8; ++s) { k1[s] = ~0u; k2[s] = ~0u; k3[s] = ~0u; }

    const ushortx* bhp = cbh + (size_t)lcol * DIM + lkq * 8;
    const ushortx* blp = cbl + (size_t)lcol * DIM + lkq * 8;

    // ---- software pipeline: prefetch B tile + csb for ct+1 before ct's MFMAs ----
    short8v nBh0 = *reinterpret_cast<const short8v*>(bhp);
    short8v nBh1 = *reinterpret_cast<const short8v*>(bhp + 32);
    short8v nBl0 = *reinterpret_cast<const short8v*>(blp);
    short8v nBl1 = *reinterpret_cast<const short8v*>(blp + 32);
    float   nCs  = cs18b[lcol];

    #pragma unroll 2
    for (int ct = 0; ct < 64; ++ct) {     // 16 codes per tile
        const short8v Bh0 = nBh0, Bh1 = nBh1, Bl0 = nBl0, Bl1 = nBl1;
        const float csb = nCs;
        const u32 cl = (u32)lcol + 16u * (u32)ct;   // this lane's current code id
        // guarded advance: last iteration re-reads same tile (in-bounds, unused)
        const int adv = (ct < 63) ? (16 * DIM) : 0;
        bhp += adv; blp += adv;
        nBh0 = *reinterpret_cast<const short8v*>(bhp);
        nBh1 = *reinterpret_cast<const short8v*>(bhp + 32);
        nBl0 = *reinterpret_cast<const short8v*>(blp);
        nBl1 = *reinterpret_cast<const short8v*>(blp + 32);
        nCs  = cs18b[cl + ((ct < 63) ? 16u : 0u)];

        #pragma unroll
        for (int t = 0; t < 2; ++t) {     // 2 independent acc chains (ILP)
            f32x4 acc = (f32x4){0.f, 0.f, 0.f, 0.f};
            acc = __builtin_amdgcn_mfma_f32_16x16x32_bf16(Ah[t][0], Bh0, acc, 0, 0, 0);
            acc = __builtin_amdgcn_mfma_f32_16x16x32_bf16(Al[t][0], Bh0, acc, 0, 0, 0);
            acc = __builtin_amdgcn_mfma_f32_16x16x32_bf16(Ah[t][0], Bl0, acc, 0, 0, 0);
            acc = __builtin_amdgcn_mfma_f32_16x16x32_bf16(Ah[t][1], Bh1, acc, 0, 0, 0);
            acc = __builtin_amdgcn_mfma_f32_16x16x32_bf16(Al[t][1], Bh1, acc, 0, 0, 0);
            acc = __builtin_amdgcn_mfma_f32_16x16x32_bf16(Ah[t][1], Bl1, acc, 0, 0, 0);
            #pragma unroll
            for (int r = 0; r < 4; ++r) {
                const float m18 = fmaf(acc[r], -524288.0f, csb);  // (cs-2dot)*2^18+bias
                const u32 key = ((u32)m18 << 10) | cl;             // trunc-cvt, monotone
                const int s = t * 4 + r;
                const u32 nk1 = umin32(key, k1[s]);
                const u32 mx  = umax32(key, k1[s]);
                const u32 nk2 = umin32(k2[s], mx);
                const u32 mx2 = umax32(k2[s], mx);
                k3[s] = umin32(k3[s], mx2);
                k1[s] = nk1; k2[s] = nk2;
            }
        }
    }

    // ---- merge the 16 col-classes per row (butterfly over lanes 16g..16g+15) ----
    #pragma unroll
    for (int s = 0; s < 8; ++s) {
        u32 a1 = k1[s], a2 = k2[s], a3 = k3[s];
        #pragma unroll
        for (int mask = 1; mask <= 8; mask <<= 1) {
            const u32 b1 = __shfl_xor(a1, mask, 64);
            const u32 b2 = __shfl_xor(a2, mask, 64);
            const u32 b3 = __shfl_xor(a3, mask, 64);
            const u32 c1 = umin32(a1, b1), d1 = umax32(a1, b1);
            const u32 c2 = umin32(a2, b2);
            const u32 o3 = umin32(umax32(d1, c2), umin32(a3, b3));
            a1 = c1; a2 = umin32(d1, c2); a3 = o3;
        }
        k1[s] = a1; k2[s] = a2; k3[s] = a3;
    }
    if (lcol < 8) {   // lane 16g+j writes slot j -> row (j>>2)*16 + g*4 + (j&3)
        const int j = lcol, g = lkq;
        const int row = (j >> 2) * 16 + g * 4 + (j & 3);
        sTop[wid][row][0] = k1[j]; sTop[wid][row][1] = k2[j]; sTop[wid][row][2] = k3[j];
    }
    __syncthreads();

    // ---- per-row final: non-hot -> min1; hot -> exact d2 (R12 chain) on candidates ----
    if (lane < 32) {
        const int row = wrow0 + lane;                  // block-local 0..127
        const u32 K1 = sTop[wid][lane][0];
        const u32 K2 = sTop[wid][lane][1];
        const u32 K3 = sTop[wid][lane][2];
        int idx = (int)(K1 & 1023u);
        const u32 m1q = K1 >> 10, m2q = K2 >> 10;
        if (m2q - m1q <= 26u) {                        // coarse hot (covers asq<=166)
            const float* xr = x + (rowbase + (size_t)row) * DIM;
            float4 xv[16];
            #pragma unroll
            for (int q = 0; q < 16; ++q) xv[q] = reinterpret_cast<const float4*>(xr)[q];
            float p[4];
            #pragma unroll
            for (int q = 0; q < 4; ++q) {              // exact quarter chains
                float a = 0.f;
                #pragma unroll
                for (int e = 0; e < 4; ++e) {
                    const float4 v = xv[4 * q + e];
                    a = fmaf(v.x, v.x, a); a = fmaf(v.y, v.y, a);
                    a = fmaf(v.z, v.z, a); a = fmaf(v.w, v.w, a);
                }
                p[q] = a;
            }
            const float asq = (p[0] + p[1]) + (p[2] + p[3]);
            const u32 Mq = (u32)fmaf(asq, 0.126f, 5.0f);   // safe ulp-derived margin
            u64 best = ~0ull;
            #pragma unroll 1
            for (int c = 0; c < 3; ++c) {
                const u32 Kc = c == 0 ? K1 : (c == 1 ? K2 : K3);
                const u32 mq = Kc >> 10;
                if (c > 0 && (mq - m1q) > Mq) break;   // keys sorted: later ones farther
                const int n = (int)(Kc & 1023u);
                const float4* cr = reinterpret_cast<const float4*>(cb + (size_t)n * DIM);
                float acc = 0.f;
                #pragma unroll
                for (int q = 0; q < 16; ++q) {         // exact sequential k-chain 0..63
                    const float4 c4 = cr[q], v = xv[q];
                    acc = fmaf(v.x, c4.x, acc); acc = fmaf(v.y, c4.y, acc);
                    acc = fmaf(v.z, c4.z, acc); acc = fmaf(v.w, c4.w, acc);
                }
                const float tt = asq - 2.0f * acc;     // ref rounding 1
                const float dd = tt + csq[n];          // ref rounding 2
                const u64 kk = ((u64)__float_as_uint(dd) << 32) | (u32)n;
                best = kk < best ? kk : best;
            }
            idx = (int)(u32)best;
        }
        sFinal[row] = idx;
        out_idx[rowbase + row] = (float)idx;
    }
    __syncthreads();

    // ---- epilogue: STE + loss in the identical 64-row units (2 per block) ----
    #pragma unroll 1
    for (int sub = 0; sub < 2; ++sub) {
        const size_t base = (rowbase + 64 * sub) * DIM;
        float lsum = 0.f;
        #pragma unroll 4
        for (int i = tid; i < 64 * DIM; i += 256) {
            const int r = i >> 6;
            const int d = i & 63;
            const int kb = sFinal[64 * sub + r];
            const float q  = cb[(size_t)kb * DIM + d];
            const float xe = x[base + i];
            out_q[base + i] = xe + (q - xe);            // STE forward, ref's rounding
            const float df = q - xe;
            lsum = fmaf(df, df, lsum);
        }
        #pragma unroll
        for (int off = 32; off; off >>= 1) lsum += __shfl_down(lsum, off, 64);
        if (lane == 0) sLoss[wid] = lsum;
        __syncthreads();
        if (tid == 0) {
            const float tot = (sLoss[0] + sLoss[1]) + (sLoss[2] + sLoss[3]);
            atomicAdd(out_loss, tot * (1.25f / 8388608.0f));
        }
        __syncthreads();
    }
}

extern "C" void kernel_launch(void* const* d_in, const int* in_sizes, int n_in,
                              void* d_out, int out_size, void* d_ws, size_t ws_size,
                              hipStream_t stream) {
    const float* x  = (const float*)d_in[0];   // 8388608
    const float* cb = (const float*)d_in[1];   // 65536
    float* out      = (float*)d_out;
    float* out_loss = out + QSIZE;             // [8388608]
    float* out_idx  = out + QSIZE + 1;         // [8388609 .. 8519680]

    float*   csq   = (float*)d_ws;             // 1024 f32
    float*   cs18b = csq + 1024;               // 1024 f32
    ushortx* cbh   = (ushortx*)(csq + 2048);   // 1024*64 bf16-hi (128 KB)
    ushortx* cbl   = cbh + KCB * DIM;          // 1024*64 bf16-lo (128 KB)

    vq_prep<<<4, 256, 0, stream>>>(cb, csq, cs18b, cbh, cbl, out_loss);
    vq_main<<<NROWS / 128, 256, 0, stream>>>(x, cb, csq, cs18b, cbh, cbl,
                                             out, out_loss, out_idx);
}

// Round 9
// 160.441 us; speedup vs baseline: 2.1966x; 1.4610x over previous
//
#include <hip/hip_runtime.h>

// VectorQuantizer forward: inputs [64,2048,64] f32, codebook [1024,64] f32.
// Outputs (f32, concat): quantized_ste [8388608], loss [1], indices-as-float [131072].
//
// Round 17: R14/R16 idle (~100us at 36% combined issue, no barriers, 4
// waves/SIMD) can't be per-wave latency (free-running waves would cover it);
// it must be a shared saturated resource. The fit: TA/L1 address processing.
// B-fragment loads are transposed gathers (addr = (lane&15)*128+(lane>>4)*16,
// 64 non-monotonic addrs, 64B gaps) -> coalescer slow path, ~3-4cy/line x 16
// lines x 4 loads x 16 waves/CU ~ 100us chip-wide. Fix: pre-swizzle the
// split codebook into MFMA-fragment-contiguous tiles (per 16-code tile: 4
// sections of 1KB = hi-k0 | hi-k1 | lo-k0 | lo-k1; section byte lane*16 =
// that lane's fragment) so every inner-loop load is the ideal pattern
// lane i -> base + i*16B, 1KB dense per instruction. Single-variable change
// vs R14 (163us): same bits, same MFMA order, same everything else.
//
// Numerics: identical to R14. bf16 hi/lo split, 3-term mfma_f32_16x16x32_bf16
// (|dot err| <= ~2e-6); argmin filter on m=cs-2dot quantized to u32 key
// ((m*2^18+bias)<<10|idx), top-3 per row via min/max network; rows with
// gap12 within the asq-scaled margin recompute EXACT d2 (sequential fmaf
// k=0..63, fl(fl(asq-2acc)+cs), u64 first-index-wins) for <=3 candidates.
// C/D layout: col=lane&15, row=(lane>>4)*4+reg (HW-verified). Loss/STE
// epilogue in identical 64-row units (2048 identical partials).

#define NROWS  131072
#define DIM    64
#define KCB    1024
#define QSIZE  (NROWS * DIM)  // 8388608

typedef unsigned long long u64;
typedef unsigned int u32;
typedef unsigned short ushortx;
typedef __attribute__((ext_vector_type(8))) short short8v;
typedef __attribute__((ext_vector_type(4))) float f32x4;

__device__ __forceinline__ u32 umin32(u32 a, u32 b) { return a < b ? a : b; }
__device__ __forceinline__ u32 umax32(u32 a, u32 b) { return a > b ? a : b; }

// RNE f32 -> bf16 (deterministic, internal-only precision split)
__device__ __forceinline__ ushortx f2bf(float f) {
    u32 u = __float_as_uint(f);
    u32 r = u + 0x7FFFu + ((u >> 16) & 1u);
    return (ushortx)(r >> 16);
}
__device__ __forceinline__ float bf2f(ushortx h) {
    return __uint_as_float(((u32)h) << 16);
}

// ---- prep: csq (exact quarter chains), cs18b key bias, and the codebook
// ---- pre-swizzled into MFMA-fragment-contiguous tiles.
// Layout (ushort units): tile ct has stride 2048; sections of 512:
//   [ct*2048 +    0 + L*8] = cbh[16ct + (L&15)][ 0 + (L>>4)*8 .. +8]   (hi k0)
//   [ct*2048 +  512 + L*8] = cbh[16ct + (L&15)][32 + (L>>4)*8 .. +8]   (hi k1)
//   [ct*2048 + 1024 + L*8] = cbl[...][ 0 + ...]                        (lo k0)
//   [ct*2048 + 1536 + L*8] = cbl[...][32 + ...]                        (lo k1)
__global__ __launch_bounds__(256) void vq_prep(const float* __restrict__ cb,
                                               float* __restrict__ csq,
                                               float* __restrict__ cs18b,
                                               ushortx* __restrict__ cbsw,
                                               float* __restrict__ loss_slot) {
    int k = blockIdx.x * 256 + threadIdx.x;
    if (k < KCB) {
        const float* c = cb + k * DIM;
        float a0 = 0.f, a1 = 0.f, a2 = 0.f, a3 = 0.f;
        #pragma unroll
        for (int d = 0; d < 16; ++d) {
            a0 = fmaf(c[d],      c[d],      a0);
            a1 = fmaf(c[16 + d], c[16 + d], a1);
            a2 = fmaf(c[32 + d], c[32 + d], a2);
            a3 = fmaf(c[48 + d], c[48 + d], a3);
        }
        const float cs = (a0 + a1) + (a2 + a3);
        csq[k] = cs;
        cs18b[k] = cs * 262144.0f + 131072.0f;   // m*2^18 + bias stays in [0,2^18)

        const int ct = k >> 4;         // tile
        const int j  = k & 15;         // code-in-tile = B-col = (lane&15)
        #pragma unroll
        for (int q = 0; q < 4; ++q) {  // k-chunk = (lane>>4)
            const int L = q * 16 + j;  // destination lane
            #pragma unroll
            for (int h = 0; h < 2; ++h) {
                union { ushortx u[8]; short8v v; } uh, ul;
                #pragma unroll
                for (int e = 0; e < 8; ++e) {
                    const float f = c[h * 32 + q * 8 + e];
                    const ushortx hh = f2bf(f);
                    uh.u[e] = hh;
                    ul.u[e] = f2bf(f - bf2f(hh));
                }
                *reinterpret_cast<short8v*>(cbsw + ct * 2048 + h * 512 + L * 8) = uh.v;
                *reinterpret_cast<short8v*>(cbsw + ct * 2048 + 1024 + h * 512 + L * 8) = ul.v;
            }
        }
    }
    if (blockIdx.x == 0 && threadIdx.x == 0) *loss_slot = 0.f;
}

// ---- main: 256 threads = 4 waves; block = 128 rows (wave owns 32 rows =
// ---- 2 MFMA rowtiles -> 2 independent acc chains; sweeps all 1024 codes) ----
__global__ __launch_bounds__(256, 4) void vq_main(const float* __restrict__ x,
                                                  const float* __restrict__ cb,
                                                  const float* __restrict__ csq,
                                                  const float* __restrict__ cs18b,
                                                  const ushortx* __restrict__ cbsw,
                                                  float* __restrict__ out_q,
                                                  float* __restrict__ out_loss,
                                                  float* __restrict__ out_idx) {
    __shared__ u32   sTop[4][32][3];
    __shared__ int   sFinal[128];
    __shared__ float sLoss[4];

    const int tid  = threadIdx.x;
    const int lane = tid & 63;
    const int wid  = tid >> 6;            // 0..3
    const size_t rowbase = (size_t)blockIdx.x * 128;
    const int wrow0 = wid * 32;           // block-local first row of this wave
    const int lcol  = lane & 15;          // A-row-in-tile / B-col / D-col
    const int lkq   = lane >> 4;          // k-chunk 0..3

    // ---- A fragments: 2 rowtiles x 2 k-halves, hi/lo bf16 splits ----
    short8v Ah[2][2], Al[2][2];
    #pragma unroll
    for (int t = 0; t < 2; ++t)
        #pragma unroll
        for (int h = 0; h < 2; ++h) {
            const float* xp = x + (rowbase + (size_t)(wrow0 + t * 16 + lcol)) * DIM
                              + h * 32 + lkq * 8;
            const float4 u0 = *reinterpret_cast<const float4*>(xp);
            const float4 u1 = *reinterpret_cast<const float4*>(xp + 4);
            const float xv[8] = {u0.x, u0.y, u0.z, u0.w, u1.x, u1.y, u1.z, u1.w};
            union { ushortx u[8]; short8v v; } uh, ul;
            #pragma unroll
            for (int j = 0; j < 8; ++j) {
                const ushortx hh = f2bf(xv[j]);
                uh.u[j] = hh;
                ul.u[j] = f2bf(xv[j] - bf2f(hh));
            }
            Ah[t][h] = uh.v;
            Al[t][h] = ul.v;
        }

    // ---- code sweep: top-3 u32 keys per row-slot (8 slots/lane) ----
    u32 k1[8], k2[8], k3[8];
    #pragma unroll
    for (int s = 0; s < 8; ++s) { k1[s] = ~0u; k2[s] = ~0u; k3[s] = ~0u; }

    u32 nlane = (u32)lcol;
    const ushortx* bp = cbsw + (size_t)lane * 8;   // ideal coalesced: lane*16B

    #pragma unroll 1
    for (int ct = 0; ct < 64; ++ct) {     // 16 codes per tile
        const short8v Bh0 = *reinterpret_cast<const short8v*>(bp);
        const short8v Bh1 = *reinterpret_cast<const short8v*>(bp + 512);
        const short8v Bl0 = *reinterpret_cast<const short8v*>(bp + 1024);
        const short8v Bl1 = *reinterpret_cast<const short8v*>(bp + 1536);
        const float csb = cs18b[nlane];
        #pragma unroll
        for (int t = 0; t < 2; ++t) {     // 2 independent acc chains (ILP)
            f32x4 acc = (f32x4){0.f, 0.f, 0.f, 0.f};
            acc = __builtin_amdgcn_mfma_f32_16x16x32_bf16(Ah[t][0], Bh0, acc, 0, 0, 0);
            acc = __builtin_amdgcn_mfma_f32_16x16x32_bf16(Al[t][0], Bh0, acc, 0, 0, 0);
            acc = __builtin_amdgcn_mfma_f32_16x16x32_bf16(Ah[t][0], Bl0, acc, 0, 0, 0);
            acc = __builtin_amdgcn_mfma_f32_16x16x32_bf16(Ah[t][1], Bh1, acc, 0, 0, 0);
            acc = __builtin_amdgcn_mfma_f32_16x16x32_bf16(Al[t][1], Bh1, acc, 0, 0, 0);
            acc = __builtin_amdgcn_mfma_f32_16x16x32_bf16(Ah[t][1], Bl1, acc, 0, 0, 0);
            #pragma unroll
            for (int r = 0; r < 4; ++r) {
                const float m18 = fmaf(acc[r], -524288.0f, csb);  // (cs-2dot)*2^18+bias
                const u32 key = ((u32)m18 << 10) | nlane;          // trunc-cvt, monotone
                const int s = t * 4 + r;
                const u32 nk1 = umin32(key, k1[s]);
                const u32 mx  = umax32(key, k1[s]);
                const u32 nk2 = umin32(k2[s], mx);
                const u32 mx2 = umax32(k2[s], mx);
                k3[s] = umin32(k3[s], mx2);
                k1[s] = nk1; k2[s] = nk2;
            }
        }
        bp += 2048; nlane += 16;
    }

    // ---- merge the 16 col-classes per row (butterfly over lanes 16g..16g+15) ----
    #pragma unroll
    for (int s = 0; s < 8; ++s) {
        u32 a1 = k1[s], a2 = k2[s], a3 = k3[s];
        #pragma unroll
        for (int mask = 1; mask <= 8; mask <<= 1) {
            const u32 b1 = __shfl_xor(a1, mask, 64);
            const u32 b2 = __shfl_xor(a2, mask, 64);
            const u32 b3 = __shfl_xor(a3, mask, 64);
            const u32 c1 = umin32(a1, b1), d1 = umax32(a1, b1);
            const u32 c2 = umin32(a2, b2);
            const u32 o3 = umin32(umax32(d1, c2), umin32(a3, b3));
            a1 = c1; a2 = umin32(d1, c2); a3 = o3;
        }
        k1[s] = a1; k2[s] = a2; k3[s] = a3;
    }
    if (lcol < 8) {   // lane 16g+j writes slot j -> row (j>>2)*16 + g*4 + (j&3)
        const int j = lcol, g = lkq;
        const int row = (j >> 2) * 16 + g * 4 + (j & 3);
        sTop[wid][row][0] = k1[j]; sTop[wid][row][1] = k2[j]; sTop[wid][row][2] = k3[j];
    }
    __syncthreads();

    // ---- per-row final: non-hot -> min1; hot -> exact d2 (R12 chain) on candidates ----
    if (lane < 32) {
        const int row = wrow0 + lane;                  // block-local 0..127
        const u32 K1 = sTop[wid][lane][0];
        const u32 K2 = sTop[wid][lane][1];
        const u32 K3 = sTop[wid][lane][2];
        int idx = (int)(K1 & 1023u);
        const u32 m1q = K1 >> 10, m2q = K2 >> 10;
        if (m2q - m1q <= 26u) {                        // coarse hot (covers asq<=166)
            const float* xr = x + (rowbase + (size_t)row) * DIM;
            float4 xv[16];
            #pragma unroll
            for (int q = 0; q < 16; ++q) xv[q] = reinterpret_cast<const float4*>(xr)[q];
            float p[4];
            #pragma unroll
            for (int q = 0; q < 4; ++q) {              // exact quarter chains
                float a = 0.f;
                #pragma unroll
                for (int e = 0; e < 4; ++e) {
                    const float4 v = xv[4 * q + e];
                    a = fmaf(v.x, v.x, a); a = fmaf(v.y, v.y, a);
                    a = fmaf(v.z, v.z, a); a = fmaf(v.w, v.w, a);
                }
                p[q] = a;
            }
            const float asq = (p[0] + p[1]) + (p[2] + p[3]);
            const u32 Mq = (u32)fmaf(asq, 0.126f, 5.0f);   // safe ulp-derived margin
            u64 best = ~0ull;
            #pragma unroll 1
            for (int c = 0; c < 3; ++c) {
                const u32 Kc = c == 0 ? K1 : (c == 1 ? K2 : K3);
                const u32 mq = Kc >> 10;
                if (c > 0 && (mq - m1q) > Mq) break;   // keys sorted: later ones farther
                const int n = (int)(Kc & 1023u);
                const float4* cr = reinterpret_cast<const float4*>(cb + (size_t)n * DIM);
                float acc = 0.f;
                #pragma unroll
                for (int q = 0; q < 16; ++q) {         // exact sequential k-chain 0..63
                    const float4 c4 = cr[q], v = xv[q];
                    acc = fmaf(v.x, c4.x, acc); acc = fmaf(v.y, c4.y, acc);
                    acc = fmaf(v.z, c4.z, acc); acc = fmaf(v.w, c4.w, acc);
                }
                const float tt = asq - 2.0f * acc;     // ref rounding 1
                const float dd = tt + csq[n];          // ref rounding 2
                const u64 kk = ((u64)__float_as_uint(dd) << 32) | (u32)n;
                best = kk < best ? kk : best;
            }
            idx = (int)(u32)best;
        }
        sFinal[row] = idx;
        out_idx[rowbase + row] = (float)idx;
    }
    __syncthreads();

    // ---- epilogue: STE + loss in the identical 64-row units (2 per block) ----
    #pragma unroll 1
    for (int sub = 0; sub < 2; ++sub) {
        const size_t base = (rowbase + 64 * sub) * DIM;
        float lsum = 0.f;
        #pragma unroll 4
        for (int i = tid; i < 64 * DIM; i += 256) {
            const int r = i >> 6;
            const int d = i & 63;
            const int kb = sFinal[64 * sub + r];
            const float q  = cb[(size_t)kb * DIM + d];
            const float xe = x[base + i];
            out_q[base + i] = xe + (q - xe);            // STE forward, ref's rounding
            const float df = q - xe;
            lsum = fmaf(df, df, lsum);
        }
        #pragma unroll
        for (int off = 32; off; off >>= 1) lsum += __shfl_down(lsum, off, 64);
        if (lane == 0) sLoss[wid] = lsum;
        __syncthreads();
        if (tid == 0) {
            const float tot = (sLoss[0] + sLoss[1]) + (sLoss[2] + sLoss[3]);
            atomicAdd(out_loss, tot * (1.25f / 8388608.0f));
        }
        __syncthreads();
    }
}

extern "C" void kernel_launch(void* const* d_in, const int* in_sizes, int n_in,
                              void* d_out, int out_size, void* d_ws, size_t ws_size,
                              hipStream_t stream) {
    const float* x  = (const float*)d_in[0];   // 8388608
    const float* cb = (const float*)d_in[1];   // 65536
    float* out      = (float*)d_out;
    float* out_loss = out + QSIZE;             // [8388608]
    float* out_idx  = out + QSIZE + 1;         // [8388609 .. 8519680]

    float*   csq   = (float*)d_ws;             // 1024 f32
    float*   cs18b = csq + 1024;               // 1024 f32
    ushortx* cbsw  = (ushortx*)(csq + 2048);   // 131072 ushorts (256 KB), 16B-aligned

    vq_prep<<<4, 256, 0, stream>>>(cb, csq, cs18b, cbsw, out_loss);
    vq_main<<<NROWS / 128, 256, 0, stream>>>(x, cb, csq, cs18b, cbsw,
                                             out, out_loss, out_idx);
}